// Round 2
// baseline (996.976 us; speedup 1.0000x reference)
//
#include <hip/hip_runtime.h>
#include <hip/hip_bf16.h>

typedef unsigned short ushort_t;

#define B_    32
#define HH    56
#define WW    56
#define CC    192
#define KK    64
#define DD    64
#define MM    8
#define HW_   3136
#define NPOS  100352

__device__ __forceinline__ float bf2f(unsigned short h) {
    return __uint_as_float(((unsigned int)h) << 16);
}
__device__ __forceinline__ unsigned short f2bf(float f) {
    unsigned int u = __float_as_uint(f);
    u += 0x7FFFu + ((u >> 16) & 1u);
    return (unsigned short)(u >> 16);
}
__device__ __forceinline__ float qgelu(float v) {
    return v / (1.0f + __expf(-1.702f * v));
}
__device__ __forceinline__ void unpack8(uint4 v, float* f) {
    f[0] = bf2f((unsigned short)(v.x & 0xffff)); f[1] = bf2f((unsigned short)(v.x >> 16));
    f[2] = bf2f((unsigned short)(v.y & 0xffff)); f[3] = bf2f((unsigned short)(v.y >> 16));
    f[4] = bf2f((unsigned short)(v.z & 0xffff)); f[5] = bf2f((unsigned short)(v.z >> 16));
    f[6] = bf2f((unsigned short)(v.w & 0xffff)); f[7] = bf2f((unsigned short)(v.w >> 16));
}

// ---------------------------------------------------------------------------
// K1: per-position fused:  pf2 = (relu(x@W1^T+b1))@W2^T + b2   [pos][64] bf16
//                          xp  = quickgelu(x@Wd^T + bd)        [pos][64] bf16
// fp32 inputs. 64 positions / block, 1568 blocks, 256 threads.
// ---------------------------------------------------------------------------
__global__ __launch_bounds__(256) void k1_meta_adapter(
    const float* __restrict__ x, const float* __restrict__ W1,
    const float* __restrict__ b1, const float* __restrict__ W2,
    const float* __restrict__ b2, const float* __restrict__ Wd,
    const float* __restrict__ bd,
    ushort_t* __restrict__ pf2g, ushort_t* __restrict__ xpg)
{
    __shared__ float wf[64 * 193];    // W1 then Wd, padded stride 193
    __shared__ float w2f[64 * 65];    // W2, padded stride 65
    __shared__ float xs[64 * 192];    // x tile fp32
    __shared__ float pf1s[64 * 64];

    const int tid = threadIdx.x;
    const int posBase = blockIdx.x * 64;

    // W1: 3072 float4, 12/thread; rows of 192 = 48 float4 (no row crossing)
    {
        const float4* src = (const float4*)W1;
        #pragma unroll
        for (int t = 0; t < 12; t++) {
            int u = tid + t * 256;
            float4 v = src[u];
            int k = u / 48, c0 = (u % 48) * 4;
            wf[k * 193 + c0 + 0] = v.x; wf[k * 193 + c0 + 1] = v.y;
            wf[k * 193 + c0 + 2] = v.z; wf[k * 193 + c0 + 3] = v.w;
        }
        const float4* s2 = (const float4*)W2;   // 1024 float4, 16 per row
        #pragma unroll
        for (int t = 0; t < 4; t++) {
            int u = tid + t * 256;
            float4 v = s2[u];
            int j = u / 16, k0 = (u % 16) * 4;
            w2f[j * 65 + k0 + 0] = v.x; w2f[j * 65 + k0 + 1] = v.y;
            w2f[j * 65 + k0 + 2] = v.z; w2f[j * 65 + k0 + 3] = v.w;
        }
        const float4* sx = (const float4*)(x + (size_t)posBase * CC);  // 3072 float4
        #pragma unroll
        for (int t = 0; t < 12; t++) {
            int u = tid + t * 256;
            float4 v = sx[u];
            xs[u * 4 + 0] = v.x; xs[u * 4 + 1] = v.y;
            xs[u * 4 + 2] = v.z; xs[u * 4 + 3] = v.w;
        }
    }
    __syncthreads();

    const int lane = tid & 63, wv = tid >> 6;
    float acc[16];

    // phase 2: pf1 = relu(x@W1^T + b1)
    {
        float bias = b1[lane];
        #pragma unroll
        for (int i = 0; i < 16; i++) acc[i] = bias;
        for (int c = 0; c < 192; c++) {
            float w = wf[lane * 193 + c];
            #pragma unroll
            for (int i = 0; i < 16; i++) acc[i] += w * xs[(wv * 16 + i) * 192 + c];
        }
        #pragma unroll
        for (int i = 0; i < 16; i++)
            pf1s[(wv * 16 + i) * 64 + lane] = acc[i] > 0.0f ? acc[i] : 0.0f;
    }
    __syncthreads();

    // phase 3: load Wd into wf (overlapped), compute pf2 = pf1@W2^T + b2
    {
        const float4* sd = (const float4*)Wd;
        #pragma unroll
        for (int t = 0; t < 12; t++) {
            int u = tid + t * 256;
            float4 v = sd[u];
            int k = u / 48, c0 = (u % 48) * 4;
            wf[k * 193 + c0 + 0] = v.x; wf[k * 193 + c0 + 1] = v.y;
            wf[k * 193 + c0 + 2] = v.z; wf[k * 193 + c0 + 3] = v.w;
        }
        float bias = b2[lane];
        #pragma unroll
        for (int i = 0; i < 16; i++) acc[i] = bias;
        for (int k = 0; k < 64; k++) {
            float w = w2f[lane * 65 + k];
            #pragma unroll
            for (int i = 0; i < 16; i++) acc[i] += w * pf1s[(wv * 16 + i) * 64 + k];
        }
        #pragma unroll
        for (int i = 0; i < 16; i++)
            pf2g[(size_t)(posBase + wv * 16 + i) * 64 + lane] = f2bf(acc[i]);
    }
    __syncthreads();

    // phase 4: xp = quickgelu(x@Wd^T + bd)
    {
        float bias = bd[lane];
        #pragma unroll
        for (int i = 0; i < 16; i++) acc[i] = bias;
        for (int c = 0; c < 192; c++) {
            float w = wf[lane * 193 + c];
            #pragma unroll
            for (int i = 0; i < 16; i++) acc[i] += w * xs[(wv * 16 + i) * 192 + c];
        }
        #pragma unroll
        for (int i = 0; i < 16; i++)
            xpg[(size_t)(posBase + wv * 16 + i) * 64 + lane] = f2bf(qgelu(acc[i]));
    }
}

// ---------------------------------------------------------------------------
// K2: mask logits -> softmax over 3136 positions (per m,b) -> masksum -> mwf
// one block per b (32 blocks), logits recomputed per pass (cheap, L2-hot).
// ---------------------------------------------------------------------------
__device__ __forceinline__ void dot8m(const uint4* row, const float* mtok, float* macc) {
    #pragma unroll
    for (int m = 0; m < 8; m++) macc[m] = 0.0f;
    #pragma unroll
    for (int c8 = 0; c8 < 8; c8++) {
        uint4 v = row[c8];
        float f[8]; unpack8(v, f);
        #pragma unroll
        for (int m = 0; m < 8; m++) {
            const float* mt = &mtok[m * 64 + c8 * 8];
            float s = f[0] * mt[0] + f[1] * mt[1] + f[2] * mt[2] + f[3] * mt[3]
                    + f[4] * mt[4] + f[5] * mt[5] + f[6] * mt[6] + f[7] * mt[7];
            macc[m] += s;
        }
    }
}

__global__ __launch_bounds__(256) void k2_mask_mwf(
    const ushort_t* __restrict__ pf2g, const float* __restrict__ mtokg,
    float* __restrict__ mwfg)
{
    __shared__ float mtok[8 * 64];
    __shared__ float masksum[HW_];
    __shared__ float wred[4][8];
    __shared__ float smx[8];
    __shared__ float sinv[8];
    __shared__ float mred[4 * 64];

    const int tid = threadIdx.x;
    const int b = blockIdx.x;
    const int lane = tid & 63, wv = tid >> 6;

    for (int i = tid; i < 512; i += 256) mtok[i] = mtokg[i];
    __syncthreads();

    const uint4* rowbase = (const uint4*)(pf2g + (size_t)b * HW_ * 64);

    // pass 1: max per m
    float lmax[8];
    #pragma unroll
    for (int m = 0; m < 8; m++) lmax[m] = -1e30f;
    for (int p = tid; p < HW_; p += 256) {
        float macc[8];
        dot8m(rowbase + (size_t)p * 8, mtok, macc);
        #pragma unroll
        for (int m = 0; m < 8; m++) lmax[m] = fmaxf(lmax[m], macc[m]);
    }
    #pragma unroll
    for (int m = 0; m < 8; m++) {
        float v = lmax[m];
        for (int off = 32; off > 0; off >>= 1) v = fmaxf(v, __shfl_down(v, off));
        lmax[m] = v;
    }
    if (lane == 0) {
        #pragma unroll
        for (int m = 0; m < 8; m++) wred[wv][m] = lmax[m];
    }
    __syncthreads();
    if (tid < 8)
        smx[tid] = fmaxf(fmaxf(wred[0][tid], wred[1][tid]), fmaxf(wred[2][tid], wred[3][tid]));
    __syncthreads();

    // pass 2: sum of exp
    float lsum[8];
    #pragma unroll
    for (int m = 0; m < 8; m++) lsum[m] = 0.0f;
    for (int p = tid; p < HW_; p += 256) {
        float macc[8];
        dot8m(rowbase + (size_t)p * 8, mtok, macc);
        #pragma unroll
        for (int m = 0; m < 8; m++) lsum[m] += __expf(macc[m] - smx[m]);
    }
    #pragma unroll
    for (int m = 0; m < 8; m++) {
        float v = lsum[m];
        for (int off = 32; off > 0; off >>= 1) v += __shfl_down(v, off);
        lsum[m] = v;
    }
    __syncthreads();   // protect wred reuse
    if (lane == 0) {
        #pragma unroll
        for (int m = 0; m < 8; m++) wred[wv][m] = lsum[m];
    }
    __syncthreads();
    if (tid < 8) {
        float s = wred[0][tid] + wred[1][tid] + wred[2][tid] + wred[3][tid];
        sinv[tid] = 1.0f / s;
    }
    __syncthreads();

    // pass 3: masksum[p] = sum_m softmax_m[p]
    for (int p = tid; p < HW_; p += 256) {
        float macc[8];
        dot8m(rowbase + (size_t)p * 8, mtok, macc);
        float ms = 0.0f;
        #pragma unroll
        for (int m = 0; m < 8; m++) ms += __expf(macc[m] - smx[m]) * sinv[m];
        masksum[p] = ms;
    }
    __syncthreads();

    // pass B: mwf[b][k] = sum_p masksum[p] * pf2[b,p,k]
    const int kk = tid & 63, part = tid >> 6;
    float a = 0.0f;
    for (int p = part; p < HW_; p += 4)
        a += masksum[p] * bf2f(pf2g[((size_t)b * HW_ + p) * 64 + kk]);
    mred[part * 64 + kk] = a;
    __syncthreads();
    if (tid < 64)
        mwfg[b * 64 + tid] = mred[tid] + mred[64 + tid] + mred[128 + tid] + mred[192 + tid];
}

// ---------------------------------------------------------------------------
// K3: conv_w[b][o] = bh[o] + sum_k mwf[b][k]*Wh[o][k]; o = tid-global, loop b.
// 144 blocks x 256 threads (36864 outputs per b). fp32 Wh/bh, bf16 out.
// ---------------------------------------------------------------------------
__global__ __launch_bounds__(256) void k3_hypernet(
    const float* __restrict__ mwfg, const float* __restrict__ Whg,
    const float* __restrict__ bhg, ushort_t* __restrict__ cwg)
{
    __shared__ float mwfs[32 * 64];
    const int tid = threadIdx.x;
    for (int i = tid; i < 2048; i += 256) mwfs[i] = mwfg[i];
    __syncthreads();

    const int o = blockIdx.x * 256 + tid;
    float wreg[64];
    const float4* src = (const float4*)(Whg + (size_t)o * 64);
    #pragma unroll
    for (int t = 0; t < 16; t++) {
        float4 v = src[t];
        wreg[t * 4 + 0] = v.x; wreg[t * 4 + 1] = v.y;
        wreg[t * 4 + 2] = v.z; wreg[t * 4 + 3] = v.w;
    }
    const float bias = bhg[o];
    for (int b = 0; b < 32; b++) {
        float a = bias;
        #pragma unroll
        for (int k = 0; k < 64; k++) a += mwfs[b * 64 + k] * wreg[k];
        cwg[(size_t)b * 36864 + o] = f2bf(a);
    }
}

// ---------------------------------------------------------------------------
// K4: per-sample 3x3 conv (64ch -> 64ch, pad 1) + quickgelu. (ws-only, bf16)
// block = (b, ytile of 4 rows); 448 blocks, 256 threads.
// thread: 4 out-channels x 14 positions register tile.
// ---------------------------------------------------------------------------
__global__ __launch_bounds__(256) void k4_conv(
    const ushort_t* __restrict__ xpg, const ushort_t* __restrict__ cwg,
    ushort_t* __restrict__ xd2g)
{
    __shared__ ushort_t cws[64 * 578];       // stride 578 (pad 2)
    __shared__ ushort_t xs[6 * 58 * 66];     // [row][col][i], i padded to 66

    const int tid = threadIdx.x;
    const int b = blockIdx.x / 14, yt = blockIdx.x % 14, y0 = yt * 4;

    {
        const uint4* src = (const uint4*)(cwg + (size_t)b * 36864);
        #pragma unroll
        for (int t = 0; t < 18; t++) {
            int u = tid + t * 256;
            uint4 v = src[u];
            int o = u / 72, s0 = (u % 72) * 8;
            unsigned int* dst = (unsigned int*)&cws[o * 578 + s0];
            dst[0] = v.x; dst[1] = v.y; dst[2] = v.z; dst[3] = v.w;
        }
    }
    for (int u = tid; u < 2784; u += 256) {
        int r = u / 464, rem = u % 464, col = rem / 8, i0 = (rem % 8) * 8;
        int gy = y0 - 1 + r, gx = col - 1;
        uint4 v;
        if (gy >= 0 && gy < 56 && gx >= 0 && gx < 56)
            v = *(const uint4*)(xpg + ((size_t)b * HW_ + gy * 56 + gx) * 64 + i0);
        else
            v = make_uint4(0, 0, 0, 0);
        unsigned int* dst = (unsigned int*)&xs[(r * 58 + col) * 66 + i0];
        dst[0] = v.x; dst[1] = v.y; dst[2] = v.z; dst[3] = v.w;
    }
    __syncthreads();

    const int og = tid & 15, pg = tid >> 4;
    const int o4 = og * 4;
    float acc[14][4];
    #pragma unroll
    for (int q = 0; q < 14; q++)
        #pragma unroll
        for (int j = 0; j < 4; j++) acc[q][j] = 0.0f;

    int base[14];
    #pragma unroll
    for (int q = 0; q < 14; q++) {
        int p = pg * 14 + q, row = p / 56, col = p - row * 56;
        base[q] = (row * 58 + col) * 66;
    }

    for (int i = 0; i < 64; i++) {
        #pragma unroll
        for (int dd = 0; dd < 9; dd++) {
            const int dy = dd / 3, dx = dd % 3;
            const int xoff = (dy * 58 + dx) * 66 + i;
            const int woff = i * 9 + dd;
            float w0 = bf2f(cws[(o4 + 0) * 578 + woff]);
            float w1 = bf2f(cws[(o4 + 1) * 578 + woff]);
            float w2 = bf2f(cws[(o4 + 2) * 578 + woff]);
            float w3 = bf2f(cws[(o4 + 3) * 578 + woff]);
            #pragma unroll
            for (int q = 0; q < 14; q++) {
                float xv = bf2f(xs[base[q] + xoff]);
                acc[q][0] += xv * w0; acc[q][1] += xv * w1;
                acc[q][2] += xv * w2; acc[q][3] += xv * w3;
            }
        }
    }

    #pragma unroll
    for (int q = 0; q < 14; q++) {
        int p = pg * 14 + q, row = p / 56, col = p - row * 56;
        size_t gpos = (size_t)b * HW_ + (size_t)(y0 + row) * 56 + col;
        #pragma unroll
        for (int j = 0; j < 4; j++)
            xd2g[gpos * 64 + o4 + j] = f2bf(qgelu(acc[q][j]));
    }
}

// ---------------------------------------------------------------------------
// K5: out = xd2@Wu^T + bu + x ;  fp32 Wu/bu/x/out. 32 pos/block, 3136 blocks.
// thread: 3 c-values x 8 positions register tile.
// ---------------------------------------------------------------------------
__global__ __launch_bounds__(256) void k5_up_res(
    const ushort_t* __restrict__ xd2g, const float* __restrict__ Wug,
    const float* __restrict__ bug, const float* __restrict__ xg,
    float* __restrict__ outg)
{
    __shared__ float wus[192 * 65];
    __shared__ ushort_t xds[32 * 64];

    const int tid = threadIdx.x;
    const size_t posBase = (size_t)blockIdx.x * 32;

    {
        const float4* su = (const float4*)Wug;   // 3072 float4, 16 per 64-row
        #pragma unroll
        for (int t = 0; t < 12; t++) {
            int u = tid + t * 256;
            float4 v = su[u];
            int c = u / 16, d0 = (u % 16) * 4;
            wus[c * 65 + d0 + 0] = v.x; wus[c * 65 + d0 + 1] = v.y;
            wus[c * 65 + d0 + 2] = v.z; wus[c * 65 + d0 + 3] = v.w;
        }
        uint4 v = ((const uint4*)(xd2g + posBase * 64))[tid];
        unsigned int* dst = (unsigned int*)&xds[tid * 8];
        dst[0] = v.x; dst[1] = v.y; dst[2] = v.z; dst[3] = v.w;
    }
    __syncthreads();

    const int lane = tid & 63, pg = tid >> 6;
    float acc[8][3];
    #pragma unroll
    for (int r = 0; r < 8; r++)
        #pragma unroll
        for (int t = 0; t < 3; t++) acc[r][t] = 0.0f;

    for (int d = 0; d < 64; d++) {
        float w0 = wus[(lane      ) * 65 + d];
        float w1 = wus[(lane +  64) * 65 + d];
        float w2 = wus[(lane + 128) * 65 + d];
        #pragma unroll
        for (int r = 0; r < 8; r++) {
            float xv = bf2f(xds[(pg * 8 + r) * 64 + d]);
            acc[r][0] += xv * w0; acc[r][1] += xv * w1; acc[r][2] += xv * w2;
        }
    }

    const float bu0 = bug[lane], bu1 = bug[lane + 64], bu2 = bug[lane + 128];
    #pragma unroll
    for (int r = 0; r < 8; r++) {
        size_t gpos = posBase + pg * 8 + r;
        const float* xrow = xg + gpos * 192;
        float* orow = outg + gpos * 192;
        orow[lane]       = acc[r][0] + bu0 + xrow[lane];
        orow[lane + 64]  = acc[r][1] + bu1 + xrow[lane + 64];
        orow[lane + 128] = acc[r][2] + bu2 + xrow[lane + 128];
    }
}

// ---------------------------------------------------------------------------
extern "C" void kernel_launch(void* const* d_in, const int* in_sizes, int n_in,
                              void* d_out, int out_size, void* d_ws, size_t ws_size,
                              hipStream_t stream) {
    const float* x    = (const float*)d_in[0];
    const float* W1   = (const float*)d_in[1];
    const float* b1   = (const float*)d_in[2];
    const float* W2   = (const float*)d_in[3];
    const float* b2   = (const float*)d_in[4];
    const float* mtok = (const float*)d_in[5];
    const float* Wh   = (const float*)d_in[6];
    const float* bh   = (const float*)d_in[7];
    const float* Wd   = (const float*)d_in[8];
    const float* bd   = (const float*)d_in[9];
    const float* Wu   = (const float*)d_in[10];
    const float* bu   = (const float*)d_in[11];
    float* out = (float*)d_out;

    char* ws = (char*)d_ws;
    ushort_t* pf2 = (ushort_t*)ws;                        // 12,845,056 B
    ushort_t* xp  = (ushort_t*)(ws + 12845056);           // 12,845,056 B
    ushort_t* xd2 = pf2;                                  // alias: pf2 dead after k2
    ushort_t* cw  = (ushort_t*)(ws + 25690112);           //  2,359,296 B
    float*    mwf = (float*)(ws + 28049408);              //      8,192 B

    k1_meta_adapter<<<1568, 256, 0, stream>>>(x, W1, b1, W2, b2, Wd, bd, pf2, xp);
    k2_mask_mwf<<<32, 256, 0, stream>>>(pf2, mtok, mwf);
    k3_hypernet<<<144, 256, 0, stream>>>(mwf, Wh, bh, cw);
    k4_conv<<<448, 256, 0, stream>>>(xp, cw, xd2);
    k5_up_res<<<3136, 256, 0, stream>>>(xd2, Wu, bu, x, out);
}

// Round 3
// 272.305 us; speedup vs baseline: 3.6613x; 3.6613x over previous
//
#include <hip/hip_runtime.h>

typedef unsigned short ushort_t;
typedef short bf16x8 __attribute__((ext_vector_type(8)));
typedef float f32x4 __attribute__((ext_vector_type(4)));

#define MFMA(a, b, c) __builtin_amdgcn_mfma_f32_16x16x32_bf16(a, b, c, 0, 0, 0)

#define B_    32
#define HW_   3136
#define NPOS  100352

__device__ __forceinline__ float bf2f(unsigned short h) {
    return __uint_as_float(((unsigned int)h) << 16);
}
__device__ __forceinline__ unsigned short f2bf(float f) {
    unsigned int u = __float_as_uint(f);
    u += 0x7FFFu + ((u >> 16) & 1u);
    return (unsigned short)(u >> 16);
}
__device__ __forceinline__ float qgelu(float v) {
    return v / (1.0f + __expf(-1.702f * v));
}
__device__ __forceinline__ void unpack8(uint4 v, float* f) {
    f[0] = bf2f((unsigned short)(v.x & 0xffff)); f[1] = bf2f((unsigned short)(v.x >> 16));
    f[2] = bf2f((unsigned short)(v.y & 0xffff)); f[3] = bf2f((unsigned short)(v.y >> 16));
    f[4] = bf2f((unsigned short)(v.z & 0xffff)); f[5] = bf2f((unsigned short)(v.z >> 16));
    f[6] = bf2f((unsigned short)(v.w & 0xffff)); f[7] = bf2f((unsigned short)(v.w >> 16));
}

// ---------------------------------------------------------------------------
// K0: pack weights into MFMA B-fragment order (bf16).
// B-frag for (kc,nt): lane holds B[k=kc*32+(lane>>4)*8+j][n=nt*16+(lane&15)].
// Stored flat: [frag-linear][lane][8].
// ---------------------------------------------------------------------------
__global__ __launch_bounds__(256) void k0_prep(
    const float* __restrict__ W1, const float* __restrict__ W2,
    const float* __restrict__ mtok, const float* __restrict__ Wd,
    const float* __restrict__ Wu,
    ushort_t* __restrict__ w1f, ushort_t* __restrict__ wdf,
    ushort_t* __restrict__ w2f, ushort_t* __restrict__ mtf,
    ushort_t* __restrict__ wuf)
{
    const int gid = blockIdx.x * 256 + threadIdx.x;
    const int stride = gridDim.x * 256;
    // W1 / Wd: K=192 (6 kc) x N=64 (4 nt): 6*4*64*8 = 12288
    for (int i = gid; i < 12288; i += stride) {
        int j = i & 7, lane = (i >> 3) & 63, nt = (i >> 9) & 3, kc = i >> 11;
        int n = nt * 16 + (lane & 15), k = kc * 32 + (lane >> 4) * 8 + j;
        w1f[i] = f2bf(W1[n * 192 + k]);
        wdf[i] = f2bf(Wd[n * 192 + k]);
    }
    // W2: K=64 (2 kc) x N=64 (4 nt): 4096
    for (int i = gid; i < 4096; i += stride) {
        int j = i & 7, lane = (i >> 3) & 63, nt = (i >> 9) & 3, kc = i >> 11;
        int n = nt * 16 + (lane & 15), k = kc * 32 + (lane >> 4) * 8 + j;
        w2f[i] = f2bf(W2[n * 64 + k]);
    }
    // mask_token: K=64 (2 kc) x N=8 padded to 16: 2*64*8 = 1024
    for (int i = gid; i < 1024; i += stride) {
        int j = i & 7, lane = (i >> 3) & 63, kc = i >> 9;
        int n = lane & 15, k = kc * 32 + (lane >> 4) * 8 + j;
        mtf[i] = (n < 8) ? f2bf(mtok[n * 64 + k]) : (ushort_t)0;
    }
    // Wu: K=64 (2 kc) x N=192 (12 nt): 2*12*64*8 = 12288
    for (int i = gid; i < 12288; i += stride) {
        int j = i & 7, lane = (i >> 3) & 63, g = i >> 9;
        int nt = g % 12, kc = g / 12;
        int n = nt * 16 + (lane & 15), k = kc * 32 + (lane >> 4) * 8 + j;
        wuf[i] = f2bf(Wu[n * 64 + k]);
    }
}

// ---------------------------------------------------------------------------
// K1 (MFMA): per 64-position block:
//   pf1 = relu(x@W1^T+b1); pf2 = pf1@W2^T+b2 -> pf2g (bf16)
//   xp  = qgelu(x@Wd^T+bd)                   -> xpg  (bf16)
//   L   = pf2@mtok^T                         -> Lg   (fp32, [pos][8])
// 1568 blocks x 256 threads (4 waves, 16 pos each).
// ---------------------------------------------------------------------------
__global__ __launch_bounds__(256) void k1_meta_adapter(
    const float* __restrict__ x, const float* __restrict__ b1,
    const float* __restrict__ b2, const float* __restrict__ bd,
    const ushort_t* __restrict__ w1f, const ushort_t* __restrict__ wdf,
    const ushort_t* __restrict__ w2f, const ushort_t* __restrict__ mtf,
    ushort_t* __restrict__ pf2g, ushort_t* __restrict__ xpg,
    float* __restrict__ Lg)
{
    __shared__ ushort_t xs[64 * 200];       // x tile bf16, stride 200 (25.6 KB)
    __shared__ ushort_t pf1s[4][16 * 72];   // per-wave pf1 / pf2 buffer (9.2 KB)

    const int tid = threadIdx.x;
    const int posBase = blockIdx.x * 64;

    // stage x -> bf16 LDS: 64 pos x 24 chunks(8) = 1536, 6/thread
    #pragma unroll
    for (int t = 0; t < 6; t++) {
        int u = tid + t * 256;
        int pos = u / 24, c8 = u % 24;
        const float4* gp = (const float4*)(x + ((size_t)(posBase + pos)) * 192 + c8 * 8);
        float4 v0 = gp[0], v1 = gp[1];
        bf16x8 r;
        r[0] = (short)f2bf(v0.x); r[1] = (short)f2bf(v0.y);
        r[2] = (short)f2bf(v0.z); r[3] = (short)f2bf(v0.w);
        r[4] = (short)f2bf(v1.x); r[5] = (short)f2bf(v1.y);
        r[6] = (short)f2bf(v1.z); r[7] = (short)f2bf(v1.w);
        *(bf16x8*)&xs[pos * 200 + c8 * 8] = r;
    }
    __syncthreads();

    const int lane = tid & 63, wv = tid >> 6;
    const int col = lane & 15, q = lane >> 4;

    // A-frags for x (reused by W1 and Wd GEMMs)
    bf16x8 A[6];
    #pragma unroll
    for (int kc = 0; kc < 6; kc++)
        A[kc] = *(const bf16x8*)&xs[(wv * 16 + col) * 200 + kc * 32 + q * 8];

    f32x4 acc1[4], acc3[4];
    #pragma unroll
    for (int nt = 0; nt < 4; nt++) { acc1[nt] = (f32x4)0.0f; acc3[nt] = (f32x4)0.0f; }

    #pragma unroll
    for (int kc = 0; kc < 6; kc++) {
        #pragma unroll
        for (int nt = 0; nt < 4; nt++) {
            bf16x8 B1 = *(const bf16x8*)(w1f + ((kc * 4 + nt) * 64 + lane) * 8);
            acc1[nt] = MFMA(A[kc], B1, acc1[nt]);
            bf16x8 Bd = *(const bf16x8*)(wdf + ((kc * 4 + nt) * 64 + lane) * 8);
            acc3[nt] = MFMA(A[kc], Bd, acc3[nt]);
        }
    }
    __syncthreads();   // all waves done reading xs; xs reusable as epilogue buf

    // pf1 = relu(acc1 + b1) -> per-wave LDS [m][72]
    #pragma unroll
    for (int nt = 0; nt < 4; nt++) {
        float bias = b1[nt * 16 + col];
        #pragma unroll
        for (int r = 0; r < 4; r++) {
            float v = acc1[nt][r] + bias;
            v = v > 0.0f ? v : 0.0f;
            pf1s[wv][(q * 4 + r) * 72 + nt * 16 + col] = f2bf(v);
        }
    }

    // GEMM2: pf2 = pf1 @ W2^T
    f32x4 acc2[4];
    #pragma unroll
    for (int nt = 0; nt < 4; nt++) acc2[nt] = (f32x4)0.0f;
    #pragma unroll
    for (int kc = 0; kc < 2; kc++) {
        bf16x8 A2 = *(const bf16x8*)&pf1s[wv][col * 72 + kc * 32 + q * 8];
        #pragma unroll
        for (int nt = 0; nt < 4; nt++) {
            bf16x8 B2 = *(const bf16x8*)(w2f + ((kc * 4 + nt) * 64 + lane) * 8);
            acc2[nt] = MFMA(A2, B2, acc2[nt]);
        }
    }

    // xp epilogue -> xs reuse [pos][72]
    #pragma unroll
    for (int nt = 0; nt < 4; nt++) {
        float bias = bd[nt * 16 + col];
        #pragma unroll
        for (int r = 0; r < 4; r++) {
            float v = qgelu(acc3[nt][r] + bias);
            xs[(wv * 16 + q * 4 + r) * 72 + nt * 16 + col] = f2bf(v);
        }
    }

    // pf2 (+b2) -> pf1s reuse (pf1 dead)
    #pragma unroll
    for (int nt = 0; nt < 4; nt++) {
        float bias = b2[nt * 16 + col];
        #pragma unroll
        for (int r = 0; r < 4; r++)
            pf1s[wv][(q * 4 + r) * 72 + nt * 16 + col] = f2bf(acc2[nt][r] + bias);
    }

    // logits: L = pf2 @ mtok^T (N=8 padded to 16)
    f32x4 Lacc = (f32x4)0.0f;
    #pragma unroll
    for (int kc = 0; kc < 2; kc++) {
        bf16x8 A3 = *(const bf16x8*)&pf1s[wv][col * 72 + kc * 32 + q * 8];
        bf16x8 Bm = *(const bf16x8*)(mtf + (kc * 64 + lane) * 8);
        Lacc = MFMA(A3, Bm, Lacc);
    }
    if (col < 8) {
        #pragma unroll
        for (int r = 0; r < 4; r++)
            Lg[((size_t)(posBase + wv * 16 + q * 4 + r)) * 8 + col] = Lacc[r];
    }
    __syncthreads();

    // cooperative coalesced writes: xp and pf2 (512 chunks each, 2/thread)
    #pragma unroll
    for (int t = 0; t < 2; t++) {
        int u = tid + t * 256;
        int pos = u >> 3, c8 = u & 7;
        uint4 vx = *(const uint4*)&xs[pos * 72 + c8 * 8];
        *(uint4*)(xpg + ((size_t)(posBase + pos)) * 64 + c8 * 8) = vx;
        uint4 vp = *(const uint4*)&pf1s[pos >> 4][(pos & 15) * 72 + c8 * 8];
        *(uint4*)(pf2g + ((size_t)(posBase + pos)) * 64 + c8 * 8) = vp;
    }
}

// ---------------------------------------------------------------------------
// K2: softmax over 3136 positions per (m,b) from precomputed logits Lg,
// masksum, then mwf[b][k] = sum_p masksum[p]*pf2[b,p,k]. 32 blocks.
// ---------------------------------------------------------------------------
__global__ __launch_bounds__(256) void k2_mask_mwf(
    const float* __restrict__ Lg, const ushort_t* __restrict__ pf2g,
    float* __restrict__ mwfg)
{
    __shared__ float masksum[HW_];
    __shared__ float wred[4][8];
    __shared__ float smx[8];
    __shared__ float sinv[8];
    __shared__ float sred[32 * 64];

    const int tid = threadIdx.x;
    const int b = blockIdx.x;
    const int lane = tid & 63, wv = tid >> 6;
    const float* Lb = Lg + (size_t)b * HW_ * 8;

    // pass 1: max per m
    float lmax[8];
    #pragma unroll
    for (int m = 0; m < 8; m++) lmax[m] = -1e30f;
    for (int p = tid; p < HW_; p += 256) {
        const float4* lp = (const float4*)(Lb + (size_t)p * 8);
        float4 a = lp[0], c = lp[1];
        lmax[0] = fmaxf(lmax[0], a.x); lmax[1] = fmaxf(lmax[1], a.y);
        lmax[2] = fmaxf(lmax[2], a.z); lmax[3] = fmaxf(lmax[3], a.w);
        lmax[4] = fmaxf(lmax[4], c.x); lmax[5] = fmaxf(lmax[5], c.y);
        lmax[6] = fmaxf(lmax[6], c.z); lmax[7] = fmaxf(lmax[7], c.w);
    }
    #pragma unroll
    for (int m = 0; m < 8; m++) {
        float v = lmax[m];
        for (int off = 32; off > 0; off >>= 1) v = fmaxf(v, __shfl_down(v, off));
        lmax[m] = v;
    }
    if (lane == 0) {
        #pragma unroll
        for (int m = 0; m < 8; m++) wred[wv][m] = lmax[m];
    }
    __syncthreads();
    if (tid < 8)
        smx[tid] = fmaxf(fmaxf(wred[0][tid], wred[1][tid]), fmaxf(wred[2][tid], wred[3][tid]));
    __syncthreads();

    // pass 2: sum of exp
    float lsum[8];
    #pragma unroll
    for (int m = 0; m < 8; m++) lsum[m] = 0.0f;
    for (int p = tid; p < HW_; p += 256) {
        const float4* lp = (const float4*)(Lb + (size_t)p * 8);
        float4 a = lp[0], c = lp[1];
        lsum[0] += __expf(a.x - smx[0]); lsum[1] += __expf(a.y - smx[1]);
        lsum[2] += __expf(a.z - smx[2]); lsum[3] += __expf(a.w - smx[3]);
        lsum[4] += __expf(c.x - smx[4]); lsum[5] += __expf(c.y - smx[5]);
        lsum[6] += __expf(c.z - smx[6]); lsum[7] += __expf(c.w - smx[7]);
    }
    #pragma unroll
    for (int m = 0; m < 8; m++) {
        float v = lsum[m];
        for (int off = 32; off > 0; off >>= 1) v += __shfl_down(v, off);
        lsum[m] = v;
    }
    __syncthreads();
    if (lane == 0) {
        #pragma unroll
        for (int m = 0; m < 8; m++) wred[wv][m] = lsum[m];
    }
    __syncthreads();
    if (tid < 8)
        sinv[tid] = 1.0f / (wred[0][tid] + wred[1][tid] + wred[2][tid] + wred[3][tid]);
    __syncthreads();

    // pass 3: masksum
    for (int p = tid; p < HW_; p += 256) {
        const float4* lp = (const float4*)(Lb + (size_t)p * 8);
        float4 a = lp[0], c = lp[1];
        float ms = __expf(a.x - smx[0]) * sinv[0] + __expf(a.y - smx[1]) * sinv[1]
                 + __expf(a.z - smx[2]) * sinv[2] + __expf(a.w - smx[3]) * sinv[3]
                 + __expf(c.x - smx[4]) * sinv[4] + __expf(c.y - smx[5]) * sinv[5]
                 + __expf(c.z - smx[6]) * sinv[6] + __expf(c.w - smx[7]) * sinv[7];
        masksum[p] = ms;
    }
    __syncthreads();

    // pass 4: mwf accumulate, vectorized: thread = (part, kgroup)
    const int part = tid >> 3, kg = tid & 7;
    float a8[8];
    #pragma unroll
    for (int j = 0; j < 8; j++) a8[j] = 0.0f;
    for (int p = part; p < HW_; p += 32) {
        float ms = masksum[p];
        uint4 v = *(const uint4*)(pf2g + ((size_t)b * HW_ + p) * 64 + kg * 8);
        float f[8]; unpack8(v, f);
        #pragma unroll
        for (int j = 0; j < 8; j++) a8[j] += ms * f[j];
    }
    #pragma unroll
    for (int j = 0; j < 8; j++) sred[part * 64 + kg * 8 + j] = a8[j];
    __syncthreads();
    if (tid < 64) {
        float s = 0.0f;
        #pragma unroll
        for (int pt = 0; pt < 32; pt++) s += sred[pt * 64 + tid];
        mwfg[b * 64 + tid] = s;
    }
}

// ---------------------------------------------------------------------------
// K3: conv_w = mwf@Wh^T + bh, written in k4's B-frag order:
// cwb[b][tap][kc][nt][lane][8] ; op = frag-linear index per b.
// 144 blocks x 256 threads.
// ---------------------------------------------------------------------------
__global__ __launch_bounds__(256) void k3_hypernet(
    const float* __restrict__ mwfg, const float* __restrict__ Whg,
    const float* __restrict__ bhg, ushort_t* __restrict__ cwb)
{
    __shared__ float mwfs[32 * 64];
    const int tid = threadIdx.x;
    for (int i = tid; i < 2048; i += 256) mwfs[i] = mwfg[i];
    __syncthreads();

    const int op = blockIdx.x * 256 + tid;     // 0..36863
    const int j = op & 7, lane = (op >> 3) & 63, nt = (op >> 9) & 3;
    const int kc = (op >> 11) & 1, tap = op >> 12;
    const int oc = nt * 16 + (lane & 15);
    const int ic = kc * 32 + (lane >> 4) * 8 + j;
    const int o = oc * 576 + ic * 9 + tap;     // Wh row

    float wreg[64];
    const float4* src = (const float4*)(Whg + (size_t)o * 64);
    #pragma unroll
    for (int t = 0; t < 16; t++) {
        float4 v = src[t];
        wreg[t * 4 + 0] = v.x; wreg[t * 4 + 1] = v.y;
        wreg[t * 4 + 2] = v.z; wreg[t * 4 + 3] = v.w;
    }
    const float bias = bhg[o];
    for (int b = 0; b < 32; b++) {
        float a = bias;
        #pragma unroll
        for (int k = 0; k < 64; k++) a += mwfs[b * 64 + k] * wreg[k];
        cwb[(size_t)b * 36864 + op] = f2bf(a);
    }
}

// ---------------------------------------------------------------------------
// K4 (MFMA): per-sample 3x3 conv + qgelu as 9 tap-GEMMs.
// block = (b, 4-row tile): 448 blocks x 128 threads (2 waves x 7 M-tiles).
// Halo LDS layout: [kc(2)][(r*58+c)][40] bf16 (20-dword stride: bank spread).
// ---------------------------------------------------------------------------
__global__ __launch_bounds__(128) void k4_conv(
    const ushort_t* __restrict__ xpg, const ushort_t* __restrict__ cwb,
    ushort_t* __restrict__ xd2g)
{
    __shared__ ushort_t xs[2 * 348 * 40];   // 55,680 B; reused as epilogue buf

    const int tid = threadIdx.x;
    const int b = blockIdx.x / 14, yt = blockIdx.x % 14, y0 = yt * 4;

    // stage haloed input: 6 rows x 58 cols x 8 chunks = 2784
    for (int u = tid; u < 2784; u += 128) {
        int r = u / 464, rem = u % 464, c = rem >> 3, c8 = rem & 7;
        int gy = y0 - 1 + r, gx = c - 1;
        uint4 v = make_uint4(0, 0, 0, 0);
        if (gy >= 0 && gy < 56 && gx >= 0 && gx < 56)
            v = *(const uint4*)(xpg + ((size_t)b * HW_ + gy * 56 + gx) * 64 + c8 * 8);
        int kc = c8 >> 2, q = c8 & 3;
        *(uint4*)&xs[kc * 13920 + (r * 58 + c) * 40 + q * 8] = v;
    }
    __syncthreads();

    const int lane = tid & 63, wv = tid >> 6;
    const int col = lane & 15, q = lane >> 4;

    // per-M-tile lane base byte-offsets (dy=dx=0 corner)
    int abase[7];
    #pragma unroll
    for (int t = 0; t < 7; t++) {
        int p = (wv * 7 + t) * 16 + col;
        int row = p / 56, cc = p - row * 56;
        abase[t] = ((row * 58 + cc) * 40 + q * 8) * 2;
    }

    f32x4 acc[7][4];
    #pragma unroll
    for (int t = 0; t < 7; t++)
        #pragma unroll
        for (int nt = 0; nt < 4; nt++) acc[t][nt] = (f32x4)0.0f;

    const ushort_t* wbase = cwb + (size_t)b * 36864;
    for (int tap = 0; tap < 9; tap++) {
        const int dy = tap / 3, dx = tap % 3;
        const int toff = (dy * 58 + dx) * 80;
        bf16x8 Bf[2][4];
        #pragma unroll
        for (int kc = 0; kc < 2; kc++)
            #pragma unroll
            for (int nt = 0; nt < 4; nt++)
                Bf[kc][nt] = *(const bf16x8*)(wbase + tap * 4096 + ((kc * 4 + nt) * 64 + lane) * 8);
        #pragma unroll
        for (int t = 0; t < 7; t++) {
            bf16x8 A0 = *(const bf16x8*)((const char*)xs + abase[t] + toff);
            bf16x8 A1 = *(const bf16x8*)((const char*)xs + 27840 + abase[t] + toff);
            #pragma unroll
            for (int nt = 0; nt < 4; nt++) {
                acc[t][nt] = MFMA(A0, Bf[0][nt], acc[t][nt]);
                acc[t][nt] = MFMA(A1, Bf[1][nt], acc[t][nt]);
            }
        }
    }
    __syncthreads();   // done with halo; reuse xs as epilogue buffer [224][72]

    #pragma unroll
    for (int t = 0; t < 7; t++) {
        int mt = wv * 7 + t;
        #pragma unroll
        for (int nt = 0; nt < 4; nt++)
            #pragma unroll
            for (int r = 0; r < 4; r++)
                xs[(mt * 16 + q * 4 + r) * 72 + nt * 16 + col] = f2bf(qgelu(acc[t][nt][r]));
    }
    __syncthreads();

    // coalesced write-out: 224 pos x 8 chunks = 1792
    for (int u = tid; u < 1792; u += 128) {
        int pos = u >> 3, c8 = u & 7;
        uint4 v = *(const uint4*)&xs[pos * 72 + c8 * 8];
        size_t gpos = (size_t)b * HW_ + (size_t)y0 * 56 + pos;
        *(uint4*)(xd2g + gpos * 64 + c8 * 8) = v;
    }
}

// ---------------------------------------------------------------------------
// K5 (MFMA): out = xd2@Wu^T + bu + x (fp32 out). 1568 blocks x 256 threads.
// ---------------------------------------------------------------------------
__global__ __launch_bounds__(256) void k5_up_res(
    const ushort_t* __restrict__ xd2g, const ushort_t* __restrict__ wuf,
    const float* __restrict__ bu, const float* __restrict__ xg,
    float* __restrict__ outg)
{
    __shared__ ushort_t xds[64 * 72];

    const int tid = threadIdx.x;
    const size_t posBase = (size_t)blockIdx.x * 64;

    #pragma unroll
    for (int t = 0; t < 2; t++) {
        int u = tid + t * 256;
        int pos = u >> 3, c8 = u & 7;
        uint4 v = *(const uint4*)(xd2g + (posBase + pos) * 64 + c8 * 8);
        *(uint4*)&xds[pos * 72 + c8 * 8] = v;
    }
    __syncthreads();

    const int lane = tid & 63, wv = tid >> 6;
    const int col = lane & 15, q = lane >> 4;

    bf16x8 A[2];
    #pragma unroll
    for (int kc = 0; kc < 2; kc++)
        A[kc] = *(const bf16x8*)&xds[(wv * 16 + col) * 72 + kc * 32 + q * 8];

    f32x4 acc[12];
    #pragma unroll
    for (int nt = 0; nt < 12; nt++) acc[nt] = (f32x4)0.0f;
    #pragma unroll
    for (int kc = 0; kc < 2; kc++)
        #pragma unroll
        for (int nt = 0; nt < 12; nt++) {
            bf16x8 B = *(const bf16x8*)(wuf + ((kc * 12 + nt) * 64 + lane) * 8);
            acc[nt] = MFMA(A[kc], B, acc[nt]);
        }

    #pragma unroll
    for (int nt = 0; nt < 12; nt++) {
        float bias = bu[nt * 16 + col];
        #pragma unroll
        for (int r = 0; r < 4; r++) {
            size_t off = (posBase + wv * 16 + q * 4 + r) * 192 + nt * 16 + col;
            outg[off] = acc[nt][r] + bias + xg[off];
        }
    }
}

// ---------------------------------------------------------------------------
extern "C" void kernel_launch(void* const* d_in, const int* in_sizes, int n_in,
                              void* d_out, int out_size, void* d_ws, size_t ws_size,
                              hipStream_t stream) {
    const float* x    = (const float*)d_in[0];
    const float* W1   = (const float*)d_in[1];
    const float* b1   = (const float*)d_in[2];
    const float* W2   = (const float*)d_in[3];
    const float* b2   = (const float*)d_in[4];
    const float* mtok = (const float*)d_in[5];
    const float* Wh   = (const float*)d_in[6];
    const float* bh   = (const float*)d_in[7];
    const float* Wd   = (const float*)d_in[8];
    const float* bd   = (const float*)d_in[9];
    const float* Wu   = (const float*)d_in[10];
    const float* bu   = (const float*)d_in[11];
    float* out = (float*)d_out;

    char* ws = (char*)d_ws;
    ushort_t* pf2 = (ushort_t*)ws;                        // 12,845,056 B
    ushort_t* xp  = (ushort_t*)(ws + 12845056);           // 12,845,056 B
    ushort_t* xd2 = pf2;                                  // alias: pf2 dead after k2
    ushort_t* cwb = (ushort_t*)(ws + 25690112);           //  2,359,296 B
    float*    mwf = (float*)(ws + 28049408);              //      8,192 B
    float*    Lg  = (float*)(ws + 28057600);              //  3,211,264 B
    ushort_t* w1f = (ushort_t*)(ws + 31268864);           //     24,576 B
    ushort_t* wdf = (ushort_t*)(ws + 31293440);           //     24,576 B
    ushort_t* w2f = (ushort_t*)(ws + 31318016);           //      8,192 B
    ushort_t* mtf = (ushort_t*)(ws + 31326208);           //      2,048 B
    ushort_t* wuf = (ushort_t*)(ws + 31328256);           //     24,576 B

    k0_prep<<<48, 256, 0, stream>>>(W1, W2, mtok, Wd, Wu, w1f, wdf, w2f, mtf, wuf);
    k1_meta_adapter<<<1568, 256, 0, stream>>>(x, b1, b2, bd, w1f, wdf, w2f, mtf,
                                              pf2, xp, Lg);
    k2_mask_mwf<<<32, 256, 0, stream>>>(Lg, pf2, mwf);
    k3_hypernet<<<144, 256, 0, stream>>>(mwf, Wh, bh, cwb);
    k4_conv<<<448, 128, 0, stream>>>(xp, cwb, xd2);
    k5_up_res<<<1568, 256, 0, stream>>>(xd2, wuf, bu, x, out);
}